// Round 7
// baseline (183.586 us; speedup 1.0000x reference)
//
#include <hip/hip_runtime.h>

// DialogueGCN on MI355X — round 6 = round 5 with aggmm staging alignment fixed.
//   prep:   x->Aatt split-bf16; w_att->Batt; (gc,aggr)->Wt[2048][512] x2; zero P guards
//   fat:    y = x@w_att (f32, row-major) ; xWt = (x@Wmix1)^T [2048][4224(+16)] bf16
//   scores: attn[n][21] f32
//   aggmm1: h1 = relu(band-MFMA(attn, xWt) + self)   [4096][512] bf16
//   l2:     h1Wt = (h1@Wmix2)^T
//   aggmm2: out = relu(band-MFMA(attn, h1Wt) + self) f32
// aggmm window base mbase=n0-16 (16-aligned -> aligned dwordx4 staging, no clamp);
// weight index w = k - r - 6; P rows padded [16 front | 4096 | 32 back] within stride 4224.

#define NN 4096
#define PSTR 4224   // padded row stride of transposed product panels
#define POFF 16     // column offset of m=0

typedef __bf16 bf16x8 __attribute__((ext_vector_type(8)));
typedef float f32x4 __attribute__((ext_vector_type(4)));
typedef unsigned short u16;
typedef unsigned int u32;

__device__ __forceinline__ u16 f2bf(float f) {
  unsigned u = __float_as_uint(f);
  unsigned r = u + 0x7FFFu + ((u >> 16) & 1u);
  return (u16)(r >> 16);
}
__device__ __forceinline__ float bf2f(u16 h) {
  return __uint_as_float(((unsigned)h) << 16);
}
__device__ __forceinline__ u32 packbf(float a, float b) {
  return (u32)f2bf(a) | ((u32)f2bf(b) << 16);
}

__device__ __forceinline__ void gload_lds16(const u16* g, u16* l) {
  __builtin_amdgcn_global_load_lds(
      (const __attribute__((address_space(1))) void*)g,
      (__attribute__((address_space(3))) void*)l, 16, 0, 0);
}

// ---------------- fused prep ----------------
// +seg G (blocks [17408,18176)): zero guard columns of xWt/h1Wt
__global__ void prep_all(const float* __restrict__ x, const float* __restrict__ w_att,
                         const float* __restrict__ w_gc1, const float* __restrict__ w_aggr1,
                         const float* __restrict__ w_gc2, const float* __restrict__ w_aggr2,
                         u16* __restrict__ Aatt, u16* __restrict__ Batt,
                         u16* __restrict__ Wt1, u16* __restrict__ Wt2,
                         u16* __restrict__ xWt, u16* __restrict__ h1Wt) {
  const int b = blockIdx.x, tid = threadIdx.x;
  if (b < 8192) {
    int idx = b * 256 + tid;
    int r = idx >> 9, c = idx & 511;
    float v = x[idx];
    u16 hi = f2bf(v), lo = f2bf(v - bf2f(hi));
    u16* row = Aatt + (size_t)r * 1536;
    row[c] = hi; row[512 + c] = lo; row[1024 + c] = hi;
  } else if (b < 9216) {
    int idx = (b - 8192) * 256 + tid;
    int j = idx >> 9, e = idx & 511;
    float v = w_att[(size_t)e * 512 + j];
    u16 hi = f2bf(v), lo = f2bf(v - bf2f(hi));
    u16* row = Batt + (size_t)j * 1536;
    row[e] = hi; row[512 + e] = hi; row[1024 + e] = lo;
  } else if (b < 17408) {
    int lay = (b >= 13312);
    int idx = (b - (lay ? 13312 : 9216)) * 256 + tid;  // over 2048*512
    const float* g = lay ? w_gc2 : w_gc1;
    const float* wa = lay ? w_aggr2 : w_aggr1;
    u16* Wt = lay ? Wt2 : Wt1;
    int j = idx >> 9, k = idx & 511;
    int p = j >> 9, jj = j & 511;
    size_t o = (size_t)k * 512 + jj;
    float v;
    if (p == 0)      v = g[o] - g[262144 + o];
    else if (p == 1) v = g[524288 + o] - g[786432 + o];
    else if (p == 2) v = g[262144 + o] + g[786432 + o];
    else             v = wa[o];
    Wt[(size_t)j * 512 + k] = f2bf(v);
  } else {
    int idx = (b - 17408) * 256 + tid;  // over 2*2048*48
    int buf = idx >= 98304;
    int id2 = idx - (buf ? 98304 : 0);
    int row = id2 / 48, c = id2 - row * 48;
    int off = (c < 16) ? c : (4096 + POFF + (c - 16));  // front 16 + back 32
    u16* Pt = buf ? h1Wt : xWt;
    Pt[(size_t)row * PSTR + off] = 0;
  }
}

// ---------------- 128x128 GEMM core (m97 structure) ----------------
__device__ __forceinline__ void gemm_core(const u16* __restrict__ A, const u16* __restrict__ Bt,
                                          int K, int lda, int ldb, size_t bm, size_t bn,
                                          u16* As, u16* Bs, f32x4 (&acc)[4][4]) {
  const int tid = threadIdx.x;
  const int lane = tid & 63;
  const int wave = tid >> 6;
  const int wr = wave >> 1, wc = wave & 1;
  const int i0 = tid * 8, i1 = i0 + 2048;
  const int ar0 = i0 >> 5, ac0 = i0 & 31;
  const int ar1 = i1 >> 5, ac1 = i1 & 31;
  const int kb = (lane >> 4) * 8;
  const int arow = wr * 64 + (lane & 15);
  const int bcol = wc * 64 + (lane & 15);

  for (int k0 = 0; k0 < K; k0 += 32) {
    gload_lds16(A + (bm + ar0) * lda + k0 + ac0, &As[i0]);
    gload_lds16(A + (bm + ar1) * lda + k0 + ac1, &As[i1]);
    gload_lds16(Bt + (bn + ar0) * ldb + k0 + ac0, &Bs[i0]);
    gload_lds16(Bt + (bn + ar1) * ldb + k0 + ac1, &Bs[i1]);
    asm volatile("s_waitcnt vmcnt(0)" ::: "memory");
    __syncthreads();
    bf16x8 af[4], bfr[4];
#pragma unroll
    for (int i = 0; i < 4; ++i) {
      af[i] = *(const bf16x8*)&As[(arow + i * 16) * 32 + kb];
      bfr[i] = *(const bf16x8*)&Bs[(bcol + i * 16) * 32 + kb];
    }
#pragma unroll
    for (int i = 0; i < 4; ++i)
#pragma unroll
      for (int j = 0; j < 4; ++j)
        acc[i][j] = __builtin_amdgcn_mfma_f32_16x16x32_bf16(af[i], bfr[j], acc[i][j], 0, 0, 0);
    __syncthreads();
  }
}

// fat GEMM: bx<4 -> y (split-bf16, K=1536, f32 row-major); else xWt (K=512, bf16 transposed)
__global__ __launch_bounds__(256, 2) void fat_gemm(const u16* __restrict__ Aatt,
                                                   const u16* __restrict__ Wt1,
                                                   const u16* __restrict__ Batt,
                                                   u16* __restrict__ xWt, float* __restrict__ y) {
  __shared__ u16 As[128 * 32];
  __shared__ u16 Bs[128 * 32];
  f32x4 acc[4][4] = {};
  const int tid = threadIdx.x;
  const int lane = tid & 63;
  const int wave = tid >> 6;
  const int wr = wave >> 1, wc = wave & 1;
  const size_t bm = (size_t)blockIdx.y * 128;
  const bool yp = blockIdx.x < 4;
  const size_t bn = yp ? (size_t)blockIdx.x * 128 : (size_t)(blockIdx.x - 4) * 128;

  if (yp)
    gemm_core(Aatt, Batt, 1536, 1536, 1536, bm, bn, As, Bs, acc);
  else
    gemm_core(Aatt, Wt1, 512, 1536, 512, bm, bn, As, Bs, acc);

  const size_t crow = bm + wr * 64 + ((lane >> 4) * 4);
  const size_t ccol = bn + wc * 64 + (lane & 15);
#pragma unroll
  for (int i = 0; i < 4; ++i)
#pragma unroll
    for (int j = 0; j < 4; ++j) {
      if (yp) {
#pragma unroll
        for (int b = 0; b < 4; ++b)
          y[(crow + i * 16 + b) * 512 + ccol + j * 16] = acc[i][j][b];
      } else {
        uint2 v;
        v.x = packbf(acc[i][j][0], acc[i][j][1]);
        v.y = packbf(acc[i][j][2], acc[i][j][3]);
        *(uint2*)(xWt + (size_t)(ccol + j * 16) * PSTR + POFF + crow + i * 16) = v;
      }
    }
}

// layer-2 GEMM: h1Wt = (h1 @ Wmix2)^T bf16 packed
__global__ __launch_bounds__(256, 2) void gemm_l2(const u16* __restrict__ h1,
                                                  const u16* __restrict__ Wt2,
                                                  u16* __restrict__ h1Wt) {
  __shared__ u16 As[128 * 32];
  __shared__ u16 Bs[128 * 32];
  f32x4 acc[4][4] = {};
  const int tid = threadIdx.x;
  const int lane = tid & 63;
  const int wave = tid >> 6;
  const int wr = wave >> 1, wc = wave & 1;
  const size_t bm = (size_t)blockIdx.y * 128;
  const size_t bn = (size_t)blockIdx.x * 128;
  gemm_core(h1, Wt2, 512, 512, 512, bm, bn, As, Bs, acc);
  const size_t crow = bm + wr * 64 + ((lane >> 4) * 4);
  const size_t ccol = bn + wc * 64 + (lane & 15);
#pragma unroll
  for (int i = 0; i < 4; ++i)
#pragma unroll
    for (int j = 0; j < 4; ++j) {
      uint2 v;
      v.x = packbf(acc[i][j][0], acc[i][j][1]);
      v.y = packbf(acc[i][j][2], acc[i][j][3]);
      *(uint2*)(h1Wt + (size_t)(ccol + j * 16) * PSTR + POFF + crow + i * 16) = v;
    }
}

// ---------------- scores + softmax (per-row, XCD-swizzled) ----------------
__global__ void attn_scores(const float* __restrict__ x, const float* __restrict__ y,
                            float* __restrict__ attn) {
  const int row = ((blockIdx.x & 7) << 9) + (blockIdx.x >> 3);
  __shared__ float ys[512];
  __shared__ float sc[21];
  const int tid = threadIdx.x;  // 256
  ys[tid] = y[(size_t)row * 512 + tid];
  ys[tid + 256] = y[(size_t)row * 512 + tid + 256];
  __syncthreads();
  const int wave = tid >> 6, lane = tid & 63;
  for (int w = wave; w < 21; w += 4) {
    int m = row + w - 10;
    float s = 0.f;
    if (0 <= m && m < NN) {
      const float* xm = x + (size_t)m * 512;
      float p = 0.f;
#pragma unroll
      for (int i = 0; i < 8; ++i) p += xm[lane + i * 64] * ys[lane + i * 64];
#pragma unroll
      for (int off = 32; off; off >>= 1) p += __shfl_xor(p, off, 64);
      s = p;
    }
    if (lane == 0) sc[w] = s;
  }
  __syncthreads();
  if (tid < 64) {
    float v = (tid < 21) ? sc[tid] : -1e30f;
    float mx = v;
#pragma unroll
    for (int off = 32; off; off >>= 1) mx = fmaxf(mx, __shfl_xor(mx, off, 64));
    float e = (tid < 21) ? __expf(v - mx) : 0.f;
    float sum = e;
#pragma unroll
    for (int off = 32; off; off >>= 1) sum += __shfl_xor(sum, off, 64);
    if (tid < 21) {
      int m = row + tid - 10;
      attn[(size_t)row * 24 + tid] = (0 <= m && m < NN) ? (e / sum) : 0.f;
    }
  }
}

// ---------------- banded aggregation via MFMA ----------------
// Window: k in [0,64) covers m = mbase + k, mbase = n0 - 16 (16-aligned).
// Weight index w = k - r - 6. A[3][16][64] bf16 masked (XOR-swz LDS);
// B [128 e][64 k] via pre-swizzled-source global_load_lds; self panel init; relu.
template <int OUT_BF16>
__global__ __launch_bounds__(256) void aggmm(const u16* __restrict__ P,
                                             const float* __restrict__ attn,
                                             const int* __restrict__ spk,
                                             void* __restrict__ out) {
  __shared__ u16 Asm[3 * 1024];
  __shared__ u16 Bls[2][128 * 64];
  __shared__ int sps[64];
  __shared__ int spn[16];
  const int tid = threadIdx.x, lane = tid & 63, wave = tid >> 6;
  const int b = blockIdx.x;
  const int n0 = (((b & 7) << 5) + (b >> 3)) << 4;  // XCD-contiguous 16-row slices
  const int mbase = n0 - 16;

  if (tid < 64) {
    int m = mbase + tid;
    sps[tid] = (0 <= m && m < NN) ? spk[m] : -9;
  } else if (tid < 80) {
    spn[tid - 64] = spk[n0 + tid - 64];
  }
  __syncthreads();

  auto STAGE = [&](int rd, int bufi) {
    int rbase = (rd % 3) * 512 + (rd / 3) * 128;
#pragma unroll
    for (int c = 0; c < 4; ++c) {
      int o = (wave * 4 + c) * 1024 + lane * 16;  // linear LDS byte offset
      int row = o >> 7;
      int sw = o ^ ((row & 7) << 4);              // pre-swizzled source (rule #21)
      int mc = mbase + ((sw & 127) >> 1);         // 8-elt aligned -> 16B-aligned addr
      gload_lds16(P + (size_t)(rbase + row) * PSTR + POFF + mc, &Bls[bufi][o >> 1]);
    }
  };

  STAGE(0, 0);

  // build masked-attention A (swizzled writes)
  for (int idx = tid; idx < 3072; idx += 256) {
    int p = idx >> 10, rem = idx & 1023, r = rem >> 6, k = rem & 63;
    int w = k - r - 6;
    float a = 0.f;
    if (0 <= w && w < 21) a = attn[(size_t)(n0 + r) * 24 + w];
    bool keep = (p == 2) || (p == 0 ? (w >= 10) : (sps[k] == spn[r]));
    u16 v = keep ? f2bf(a) : (u16)0;
    int byte = (r * 128 + k * 2) ^ ((r & 7) << 4);
    *(u16*)((char*)Asm + p * 2048 + byte) = v;
  }
  __syncthreads();

  bf16x8 afr[3][2];
#pragma unroll
  for (int p = 0; p < 3; ++p)
#pragma unroll
    for (int ks = 0; ks < 2; ++ks) {
      int byte = ((lane & 15) * 128 + (ks * 32 + (lane >> 4) * 8) * 2) ^ ((lane & 7) << 4);
      afr[p][ks] = *(const bf16x8*)((const char*)Asm + p * 2048 + byte);
    }

  f32x4 acc[2];
  for (int rd = 0; rd < 12; ++rd) {
    if (rd < 11) {
      STAGE(rd + 1, (rd + 1) & 1);
      asm volatile("s_waitcnt vmcnt(4)" ::: "memory");
    } else {
      asm volatile("s_waitcnt vmcnt(0)" ::: "memory");
    }
    __syncthreads();
    const int p = rd % 3, e0 = (rd / 3) * 128;
    if (p == 0) {
#pragma unroll
      for (int q = 0; q < 2; ++q) {
        int e = e0 + (wave * 2 + q) * 16 + (lane & 15);
        uint2 sv = *(const uint2*)(P + (size_t)(1536 + e) * PSTR + POFF + n0 + ((lane >> 4) << 2));
        acc[q][0] = bf2f((u16)sv.x);
        acc[q][1] = bf2f((u16)(sv.x >> 16));
        acc[q][2] = bf2f((u16)sv.y);
        acc[q][3] = bf2f((u16)(sv.y >> 16));
      }
    }
#pragma unroll
    for (int q = 0; q < 2; ++q) {
      int col = (wave * 2 + q) * 16 + (lane & 15);
#pragma unroll
      for (int ks = 0; ks < 2; ++ks) {
        int byte = (col * 128 + (ks * 32 + (lane >> 4) * 8) * 2) ^ ((col & 7) << 4);
        bf16x8 bfr = *(const bf16x8*)((const char*)&Bls[rd & 1][0] + byte);
        acc[q] = __builtin_amdgcn_mfma_f32_16x16x32_bf16(afr[p][ks], bfr, acc[q], 0, 0, 0);
      }
    }
    if (p == 2) {
#pragma unroll
      for (int q = 0; q < 2; ++q) {
        int e = e0 + (wave * 2 + q) * 16 + (lane & 15);
#pragma unroll
        for (int bb = 0; bb < 4; ++bb) {
          int r = n0 + ((lane >> 4) << 2) + bb;
          float v = fmaxf(acc[q][bb], 0.f);
          if (OUT_BF16)
            ((u16*)out)[(size_t)r * 512 + e] = f2bf(v);
          else
            ((float*)out)[(size_t)r * 512 + e] = v;
        }
      }
    }
    __syncthreads();
  }
}

// ---------------- launch ----------------
extern "C" void kernel_launch(void* const* d_in, const int* in_sizes, int n_in,
                              void* d_out, int out_size, void* d_ws, size_t ws_size,
                              hipStream_t stream) {
  const float* x = (const float*)d_in[0];
  const int* spk = (const int*)d_in[1];
  const float* w_gc1 = (const float*)d_in[2];
  const float* w_gc2 = (const float*)d_in[3];
  const float* w_att = (const float*)d_in[4];
  const float* w_aggr1 = (const float*)d_in[5];
  const float* w_aggr2 = (const float*)d_in[6];

  char* p = (char*)d_ws;
  u16* Aatt = (u16*)p;  p += (size_t)NN * 1536 * 2;    // 12.6 MB
  u16* Batt = (u16*)p;  p += (size_t)512 * 1536 * 2;   // 1.6 MB
  u16* Wt1 = (u16*)p;   p += (size_t)2048 * 512 * 2;   // 2.1 MB
  u16* Wt2 = (u16*)p;   p += (size_t)2048 * 512 * 2;   // 2.1 MB
  float* y = (float*)p; p += (size_t)NN * 512 * 4;     // 8.4 MB
  float* attn = (float*)p; p += (size_t)NN * 24 * 4;   // 0.4 MB
  u16* xWt = (u16*)p;   p += (size_t)2048 * PSTR * 2;  // 17.3 MB
  u16* h1 = (u16*)p;    p += (size_t)NN * 512 * 2;     // 4.2 MB
  u16* h1Wt = (u16*)p;  p += (size_t)2048 * PSTR * 2;  // 17.3 MB (~66 MB total)

  prep_all<<<18176, 256, 0, stream>>>(x, w_att, w_gc1, w_aggr1, w_gc2, w_aggr2,
                                      Aatt, Batt, Wt1, Wt2, xWt, h1Wt);

  fat_gemm<<<dim3(20, 32), 256, 0, stream>>>(Aatt, Wt1, Batt, xWt, y);

  attn_scores<<<NN, 256, 0, stream>>>(x, y, attn);

  aggmm<1><<<256, 256, 0, stream>>>(xWt, attn, spk, h1);

  gemm_l2<<<dim3(16, 32), 256, 0, stream>>>(h1, Wt2, h1Wt);

  aggmm<0><<<256, 256, 0, stream>>>(h1Wt, attn, spk, d_out);
}

// Round 9
// 121.218 us; speedup vs baseline: 1.5145x; 1.5145x over previous
//
#include <hip/hip_runtime.h>

// DialogueGCN on MI355X — round 8 = round 7 + the missing lgkmcnt(0) before the
// second barrier of the 2-phase GEMM core (LDS read-completion race fix).
// Structure: prep -> fat_gemm(y + xW) -> gather1 -> gemm_l2 -> gather2.

#define NN 4096

typedef __bf16 bf16x8 __attribute__((ext_vector_type(8)));
typedef float f32x4 __attribute__((ext_vector_type(4)));
typedef unsigned short u16;
typedef unsigned int u32;

__device__ __forceinline__ u16 f2bf(float f) {
  unsigned u = __float_as_uint(f);
  unsigned r = u + 0x7FFFu + ((u >> 16) & 1u);
  return (u16)(r >> 16);
}
__device__ __forceinline__ float bf2f(u16 h) {
  return __uint_as_float(((unsigned)h) << 16);
}
__device__ __forceinline__ u32 packbf(float a, float b) {
  return (u32)f2bf(a) | ((u32)f2bf(b) << 16);
}

__device__ __forceinline__ void gload_lds16(const u16* g, u16* l) {
  __builtin_amdgcn_global_load_lds(
      (const __attribute__((address_space(1))) void*)g,
      (__attribute__((address_space(3))) void*)l, 16, 0, 0);
}

// ---------------- fused prep ----------------
// seg A: x -> Aatt [N][1536] = [hi|lo|hi];  seg B: w_att -> Batt [512][1536]=[hi|hi|lo]
// seg W: Wt[2048 j][512 k], col-panels p0:gc0-gc1 p1:gc2-gc3 p2:gc1+gc3 p3:w_aggr
__global__ void prep_all(const float* __restrict__ x, const float* __restrict__ w_att,
                         const float* __restrict__ w_gc1, const float* __restrict__ w_aggr1,
                         const float* __restrict__ w_gc2, const float* __restrict__ w_aggr2,
                         u16* __restrict__ Aatt, u16* __restrict__ Batt,
                         u16* __restrict__ Wt1, u16* __restrict__ Wt2) {
  const int b = blockIdx.x, tid = threadIdx.x;
  if (b < 8192) {
    int idx = b * 256 + tid;
    int r = idx >> 9, c = idx & 511;
    float v = x[idx];
    u16 hi = f2bf(v), lo = f2bf(v - bf2f(hi));
    u16* row = Aatt + (size_t)r * 1536;
    row[c] = hi; row[512 + c] = lo; row[1024 + c] = hi;
  } else if (b < 9216) {
    int idx = (b - 8192) * 256 + tid;
    int j = idx >> 9, e = idx & 511;
    float v = w_att[(size_t)e * 512 + j];
    u16 hi = f2bf(v), lo = f2bf(v - bf2f(hi));
    u16* row = Batt + (size_t)j * 1536;
    row[e] = hi; row[512 + e] = hi; row[1024 + e] = lo;
  } else {
    int lay = (b >= 13312);
    int idx = (b - (lay ? 13312 : 9216)) * 256 + tid;  // over 2048*512
    const float* g = lay ? w_gc2 : w_gc1;
    const float* wa = lay ? w_aggr2 : w_aggr1;
    u16* Wt = lay ? Wt2 : Wt1;
    int j = idx >> 9, k = idx & 511;
    int p = j >> 9, jj = j & 511;
    size_t o = (size_t)k * 512 + jj;
    float v;
    if (p == 0)      v = g[o] - g[262144 + o];
    else if (p == 1) v = g[524288 + o] - g[786432 + o];
    else if (p == 2) v = g[262144 + o] + g[786432 + o];
    else             v = wa[o];
    Wt[(size_t)j * 512 + k] = f2bf(v);
  }
}

// XCD-aware swizzle of a 2D grid (total blocks divisible by 8)
__device__ __forceinline__ void xcd_swz(int gx, int& bx, int& by) {
  int lid = by * gx + bx;
  int cpx = (gx * (int)gridDim.y) >> 3;
  int nl = (lid & 7) * cpx + (lid >> 3);
  by = nl / gx;
  bx = nl - by * gx;
}

// ---------------- 128x128 GEMM core — 2-phase double-buffered ----------------
// Counted vmcnt(4) keeps next tile's loads in flight across the compute phase;
// lgkmcnt(0)+sched_barrier before the closing s_barrier guarantees this wave's
// ds_reads COMPLETED before any wave may overwrite the buffer (round-7 race fix).
__device__ __forceinline__ void gemm_core(const u16* __restrict__ A, const u16* __restrict__ Bt,
                                          int K, int lda, int ldb, size_t bm, size_t bn,
                                          u16 (&As)[2][4096], u16 (&Bs)[2][4096],
                                          f32x4 (&acc)[4][4]) {
  const int tid = threadIdx.x;
  const int lane = tid & 63;
  const int wave = tid >> 6;
  const int wr = wave >> 1, wc = wave & 1;
  const int i0 = tid * 8, i1 = i0 + 2048;
  const int ar0 = i0 >> 5, ac0 = i0 & 31;
  const int ar1 = i1 >> 5, ac1 = i1 & 31;
  const int kb = (lane >> 4) * 8;
  const int arow = wr * 64 + (lane & 15);
  const int bcol = wc * 64 + (lane & 15);
  const int nt = K >> 5;

  auto STAGE = [&](int t, int bi) {
    const int k0 = t << 5;
    gload_lds16(A + (bm + ar0) * lda + k0 + ac0, &As[bi][i0]);
    gload_lds16(A + (bm + ar1) * lda + k0 + ac1, &As[bi][i1]);
    gload_lds16(Bt + (bn + ar0) * ldb + k0 + ac0, &Bs[bi][i0]);
    gload_lds16(Bt + (bn + ar1) * ldb + k0 + ac1, &Bs[bi][i1]);
  };

  STAGE(0, 0);
  for (int t = 0; t < nt; ++t) {
    const int cur = t & 1;
    if (t + 1 < nt) {
      STAGE(t + 1, cur ^ 1);                            // next tile in flight over compute
      asm volatile("s_waitcnt vmcnt(4)" ::: "memory");  // tile t's 4 loads landed in LDS
    } else {
      asm volatile("s_waitcnt vmcnt(0)" ::: "memory");
    }
    __builtin_amdgcn_s_barrier();
    asm volatile("" ::: "memory");  // pin LDS reads below barrier
    bf16x8 af[4], bfr[4];
#pragma unroll
    for (int i = 0; i < 4; ++i) {
      af[i] = *(const bf16x8*)&As[cur][(arow + i * 16) * 32 + kb];
      bfr[i] = *(const bf16x8*)&Bs[cur][(bcol + i * 16) * 32 + kb];
    }
#pragma unroll
    for (int i = 0; i < 4; ++i)
#pragma unroll
      for (int j = 0; j < 4; ++j)
        acc[i][j] = __builtin_amdgcn_mfma_f32_16x16x32_bf16(af[i], bfr[j], acc[i][j], 0, 0, 0);
    // RACE FIX: ds_reads must be COMPLETE (not just issued) before the barrier,
    // else another wave's next STAGE overwrites LDS under an in-flight read.
    asm volatile("s_waitcnt lgkmcnt(0)" ::: "memory");
    __builtin_amdgcn_sched_barrier(0);
    __builtin_amdgcn_s_barrier();
  }
}

// fat GEMM: bx<4 -> y panel (split-bf16, K=1536, f32 out); else xW panel (K=512, bf16)
__global__ __launch_bounds__(256, 2) void fat_gemm(const u16* __restrict__ Aatt,
                                                   const u16* __restrict__ Wt1,
                                                   const u16* __restrict__ Batt,
                                                   u16* __restrict__ xW, float* __restrict__ y) {
  __shared__ u16 As[2][4096];
  __shared__ u16 Bs[2][4096];
  f32x4 acc[4][4] = {};
  const int tid = threadIdx.x;
  const int lane = tid & 63;
  const int wave = tid >> 6;
  const int wr = wave >> 1, wc = wave & 1;
  int bx = blockIdx.x, by = blockIdx.y;
  xcd_swz(20, bx, by);
  const size_t bm = (size_t)by * 128;
  const bool yp = bx < 4;
  const size_t bn = yp ? (size_t)bx * 128 : (size_t)(bx - 4) * 128;

  if (yp)
    gemm_core(Aatt, Batt, 1536, 1536, 1536, bm, bn, As, Bs, acc);
  else
    gemm_core(Aatt, Wt1, 512, 1536, 512, bm, bn, As, Bs, acc);

  const size_t crow = bm + wr * 64 + ((lane >> 4) * 4);
  const size_t ccol = bn + wc * 64 + (lane & 15);
#pragma unroll
  for (int i = 0; i < 4; ++i)
#pragma unroll
    for (int j = 0; j < 4; ++j)
#pragma unroll
      for (int b = 0; b < 4; ++b) {
        size_t r = crow + i * 16 + b, c = ccol + j * 16;
        if (yp)
          y[r * 512 + c] = acc[i][j][b];
        else
          xW[r * 2048 + c] = f2bf(acc[i][j][b]);
      }
}

// layer-2 GEMM: h1W = h1 @ Wt2^T, K=512, bf16 out, ldc=2048
__global__ __launch_bounds__(256, 2) void gemm_l2(const u16* __restrict__ h1,
                                                  const u16* __restrict__ Wt2,
                                                  u16* __restrict__ h1W) {
  __shared__ u16 As[2][4096];
  __shared__ u16 Bs[2][4096];
  f32x4 acc[4][4] = {};
  const int tid = threadIdx.x;
  const int lane = tid & 63;
  const int wave = tid >> 6;
  const int wr = wave >> 1, wc = wave & 1;
  int bx = blockIdx.x, by = blockIdx.y;
  xcd_swz(16, bx, by);
  const size_t bm = (size_t)by * 128;
  const size_t bn = (size_t)bx * 128;
  gemm_core(h1, Wt2, 512, 512, 512, bm, bn, As, Bs, acc);
  const size_t crow = bm + wr * 64 + ((lane >> 4) * 4);
  const size_t ccol = bn + wc * 64 + (lane & 15);
#pragma unroll
  for (int i = 0; i < 4; ++i)
#pragma unroll
    for (int j = 0; j < 4; ++j)
#pragma unroll
      for (int b = 0; b < 4; ++b) {
        size_t r = crow + i * 16 + b, c = ccol + j * 16;
        h1W[r * 2048 + c] = f2bf(acc[i][j][b]);
      }
}

// XCD-contiguous row mapping: 4096 blocks, block b -> XCD b%8, contiguous 512-row slice.
__device__ __forceinline__ int xcd_row(int b) { return (b & 7) * 512 + (b >> 3); }

// ---------------- gather1: scores + softmax + banded aggregate + relu ----------------
__global__ void gather1(const float* __restrict__ x, const float* __restrict__ y,
                        const u16* __restrict__ xW, const int* __restrict__ spk,
                        float* __restrict__ attn, u16* __restrict__ h1) {
  const int n = xcd_row(blockIdx.x);
  const int tid = threadIdx.x;
  __shared__ float ys[512];
  __shared__ float sc[21];
  __shared__ float av[21], apv[21], asv[21];
  __shared__ int sps[21];
  const int mysp = spk[n];
  ys[tid] = y[(size_t)n * 512 + tid];
  ys[tid + 256] = y[(size_t)n * 512 + tid + 256];
  if (tid < 21) {
    int m = n + tid - 10;
    sps[tid] = (0 <= m && m < NN) ? spk[m] : -9;
  }
  __syncthreads();
  const int wave = tid >> 6, lane = tid & 63;
  for (int w = wave; w < 21; w += 4) {
    int m = n + w - 10;
    float s = 0.f;
    if (0 <= m && m < NN) {
      const float* xm = x + (size_t)m * 512;
      float p = 0.f;
#pragma unroll
      for (int i = 0; i < 8; ++i) p += xm[lane + i * 64] * ys[lane + i * 64];
#pragma unroll
      for (int off = 32; off; off >>= 1) p += __shfl_xor(p, off, 64);
      s = p;
    }
    if (lane == 0) sc[w] = s;
  }
  __syncthreads();
  if (tid < 64) {
    float v = (tid < 21) ? sc[tid] : -1e30f;
    float mx = v;
#pragma unroll
    for (int off = 32; off; off >>= 1) mx = fmaxf(mx, __shfl_xor(mx, off, 64));
    float e = (tid < 21) ? __expf(v - mx) : 0.f;
    float sum = e;
#pragma unroll
    for (int off = 32; off; off >>= 1) sum += __shfl_xor(sum, off, 64);
    if (tid < 21) {
      int m = n + tid - 10;
      float a = (0 <= m && m < NN) ? (e / sum) : 0.f;
      av[tid] = a;
      apv[tid] = (tid >= 10) ? a : 0.f;           // m >= n
      asv[tid] = (sps[tid] == mysp) ? a : 0.f;    // same speaker
      attn[(size_t)n * 24 + tid] = a;
    }
  }
  __syncthreads();
  const u32* self = (const u32*)(xW + (size_t)n * 2048);
  u32 hv = self[768 + tid];
  float a0 = bf2f((u16)hv), a1 = bf2f((u16)(hv >> 16));
  for (int w = 0; w < 21; ++w) {
    int m = n + w - 10;
    if (m < 0 || m >= NN) continue;
    float a = av[w], ap = apv[w], s2 = asv[w];
    const u32* row = (const u32*)(xW + (size_t)m * 2048);
    u32 vp = row[tid], vs = row[256 + tid], va = row[512 + tid];
    a0 += ap * bf2f((u16)vp) + s2 * bf2f((u16)vs) + a * bf2f((u16)va);
    a1 += ap * bf2f((u16)(vp >> 16)) + s2 * bf2f((u16)(vs >> 16)) + a * bf2f((u16)(va >> 16));
  }
  ((u32*)(h1 + (size_t)n * 512))[tid] = packbf(fmaxf(a0, 0.f), fmaxf(a1, 0.f));
}

// ---------------- gather2: banded aggregate + relu -> fp32 out ----------------
__global__ void gather2(const u16* __restrict__ h1W, const float* __restrict__ attn,
                        const int* __restrict__ spk, float* __restrict__ out) {
  const int n = xcd_row(blockIdx.x);
  const int tid = threadIdx.x;
  __shared__ float av[21], apv[21], asv[21];
  if (tid < 21) {
    int m = n + tid - 10;
    float a = attn[(size_t)n * 24 + tid];
    int sp = (0 <= m && m < NN) ? spk[m] : -9;
    av[tid] = a;
    apv[tid] = (tid >= 10) ? a : 0.f;
    asv[tid] = (sp == spk[n]) ? a : 0.f;
  }
  __syncthreads();
  const u32* self = (const u32*)(h1W + (size_t)n * 2048);
  u32 hv = self[768 + tid];
  float a0 = bf2f((u16)hv), a1 = bf2f((u16)(hv >> 16));
  for (int w = 0; w < 21; ++w) {
    int m = n + w - 10;
    if (m < 0 || m >= NN) continue;
    float a = av[w], ap = apv[w], s2 = asv[w];
    const u32* row = (const u32*)(h1W + (size_t)m * 2048);
    u32 vp = row[tid], vs = row[256 + tid], va = row[512 + tid];
    a0 += ap * bf2f((u16)vp) + s2 * bf2f((u16)vs) + a * bf2f((u16)va);
    a1 += ap * bf2f((u16)(vp >> 16)) + s2 * bf2f((u16)(vs >> 16)) + a * bf2f((u16)(va >> 16));
  }
  float* o = out + (size_t)n * 512 + tid * 2;
  o[0] = fmaxf(a0, 0.f);
  o[1] = fmaxf(a1, 0.f);
}

// ---------------- launch ----------------
extern "C" void kernel_launch(void* const* d_in, const int* in_sizes, int n_in,
                              void* d_out, int out_size, void* d_ws, size_t ws_size,
                              hipStream_t stream) {
  const float* x = (const float*)d_in[0];
  const int* spk = (const int*)d_in[1];
  const float* w_gc1 = (const float*)d_in[2];
  const float* w_gc2 = (const float*)d_in[3];
  const float* w_att = (const float*)d_in[4];
  const float* w_aggr1 = (const float*)d_in[5];
  const float* w_aggr2 = (const float*)d_in[6];

  char* p = (char*)d_ws;
  u16* Aatt = (u16*)p;  p += (size_t)NN * 1536 * 2;    // 12.6 MB
  u16* Batt = (u16*)p;  p += (size_t)512 * 1536 * 2;   // 1.6 MB
  u16* Wt1 = (u16*)p;   p += (size_t)2048 * 512 * 2;   // 2.1 MB
  u16* Wt2 = (u16*)p;   p += (size_t)2048 * 512 * 2;   // 2.1 MB
  float* y = (float*)p; p += (size_t)NN * 512 * 4;     // 8.4 MB
  float* attn = (float*)p; p += (size_t)NN * 24 * 4;   // 0.4 MB
  u16* xW = (u16*)p;    p += (size_t)NN * 2048 * 2;    // 16.8 MB
  u16* h1 = (u16*)p;    p += (size_t)NN * 512 * 2;     // 4.2 MB
  u16* h1W = (u16*)p;   p += (size_t)NN * 2048 * 2;    // 16.8 MB (~65 MB total)

  prep_all<<<17408, 256, 0, stream>>>(x, w_att, w_gc1, w_aggr1, w_gc2, w_aggr2,
                                      Aatt, Batt, Wt1, Wt2);

  fat_gemm<<<dim3(20, 32), 256, 0, stream>>>(Aatt, Wt1, Batt, xW, y);

  gather1<<<NN, 256, 0, stream>>>(x, y, xW, spk, attn, h1);

  gemm_l2<<<dim3(16, 32), 256, 0, stream>>>(h1, Wt2, h1W);

  gather2<<<NN, 256, 0, stream>>>(h1W, attn, spk, (float*)d_out);
}

// Round 10
// 112.463 us; speedup vs baseline: 1.6324x; 1.0779x over previous
//
#include <hip/hip_runtime.h>

// DialogueGCN on MI355X — round 9 = round 8 with the GEMM core rebuilt:
//   BK=64 LDS tiles (128B rows) + T2 XOR swizzle (chunk ^= row&7) applied as
//   pre-swizzled global SOURCE + swizzled fragment READ (rule #21, involution),
//   killing the 8-way bank conflict of the BK=32 core (rows at 64B stride).
//   Counted vmcnt(8), lgkmcnt(0)+sched_barrier before closing s_barrier.
// Structure: prep -> fat_gemm(y + xW) -> gather1 -> gemm_l2 -> gather2.

#define NN 4096

typedef __bf16 bf16x8 __attribute__((ext_vector_type(8)));
typedef float f32x4 __attribute__((ext_vector_type(4)));
typedef unsigned short u16;
typedef unsigned int u32;

__device__ __forceinline__ u16 f2bf(float f) {
  unsigned u = __float_as_uint(f);
  unsigned r = u + 0x7FFFu + ((u >> 16) & 1u);
  return (u16)(r >> 16);
}
__device__ __forceinline__ float bf2f(u16 h) {
  return __uint_as_float(((unsigned)h) << 16);
}
__device__ __forceinline__ u32 packbf(float a, float b) {
  return (u32)f2bf(a) | ((u32)f2bf(b) << 16);
}

__device__ __forceinline__ void gload_lds16(const u16* g, u16* l) {
  __builtin_amdgcn_global_load_lds(
      (const __attribute__((address_space(1))) void*)g,
      (__attribute__((address_space(3))) void*)l, 16, 0, 0);
}

// ---------------- fused prep ----------------
// seg A: x -> Aatt [N][1536] = [hi|lo|hi];  seg B: w_att -> Batt [512][1536]=[hi|hi|lo]
// seg W: Wt[2048 j][512 k], col-panels p0:gc0-gc1 p1:gc2-gc3 p2:gc1+gc3 p3:w_aggr
__global__ void prep_all(const float* __restrict__ x, const float* __restrict__ w_att,
                         const float* __restrict__ w_gc1, const float* __restrict__ w_aggr1,
                         const float* __restrict__ w_gc2, const float* __restrict__ w_aggr2,
                         u16* __restrict__ Aatt, u16* __restrict__ Batt,
                         u16* __restrict__ Wt1, u16* __restrict__ Wt2) {
  const int b = blockIdx.x, tid = threadIdx.x;
  if (b < 8192) {
    int idx = b * 256 + tid;
    int r = idx >> 9, c = idx & 511;
    float v = x[idx];
    u16 hi = f2bf(v), lo = f2bf(v - bf2f(hi));
    u16* row = Aatt + (size_t)r * 1536;
    row[c] = hi; row[512 + c] = lo; row[1024 + c] = hi;
  } else if (b < 9216) {
    int idx = (b - 8192) * 256 + tid;
    int j = idx >> 9, e = idx & 511;
    float v = w_att[(size_t)e * 512 + j];
    u16 hi = f2bf(v), lo = f2bf(v - bf2f(hi));
    u16* row = Batt + (size_t)j * 1536;
    row[e] = hi; row[512 + e] = hi; row[1024 + e] = lo;
  } else {
    int lay = (b >= 13312);
    int idx = (b - (lay ? 13312 : 9216)) * 256 + tid;  // over 2048*512
    const float* g = lay ? w_gc2 : w_gc1;
    const float* wa = lay ? w_aggr2 : w_aggr1;
    u16* Wt = lay ? Wt2 : Wt1;
    int j = idx >> 9, k = idx & 511;
    int p = j >> 9, jj = j & 511;
    size_t o = (size_t)k * 512 + jj;
    float v;
    if (p == 0)      v = g[o] - g[262144 + o];
    else if (p == 1) v = g[524288 + o] - g[786432 + o];
    else if (p == 2) v = g[262144 + o] + g[786432 + o];
    else             v = wa[o];
    Wt[(size_t)j * 512 + k] = f2bf(v);
  }
}

// XCD-aware swizzle of a 2D grid (total blocks divisible by 8)
__device__ __forceinline__ void xcd_swz(int gx, int& bx, int& by) {
  int lid = by * gx + bx;
  int cpx = (gx * (int)gridDim.y) >> 3;
  int nl = (lid & 7) * cpx + (lid >> 3);
  by = nl / gx;
  bx = nl - by * gx;
}

// ---------------- 128x128 GEMM core — BK=64, swizzled, double-buffered ----------------
// LDS tile [128 r][64 k] bf16: row = 128B = 8 chunks of 16B. Swizzle: data for
// k-chunk c of row r lives at LDS chunk c^(r&7). global_load_lds dest is linear;
// the SOURCE column is pre-swizzled; fragment reads apply the same XOR.
// Fragment-read banks: lanes 0-15 (rows r..r+15, fixed c) -> slots c^(r&7)
// cover all 8 -> 2 lanes/bank-group = conflict-free.
__device__ __forceinline__ void gemm_core(const u16* __restrict__ A, const u16* __restrict__ Bt,
                                          int K, int lda, int ldb, size_t bm, size_t bn,
                                          u16 (&As)[2][8192], u16 (&Bs)[2][8192],
                                          f32x4 (&acc)[4][4]) {
  const int tid = threadIdx.x;
  const int lane = tid & 63;
  const int wave = tid >> 6;
  const int wr = wave >> 1, wc = wave & 1;
  const int arow = wr * 64 + (lane & 15);
  const int bcol = wc * 64 + (lane & 15);
  const int nt = K >> 6;

  // staging geometry: 4 chunks/thread per matrix; linear byte offset o,
  // dest row r=o>>7, chunk c=(o>>4)&7, source col = ((c ^ (r&7)) << 3)
  auto STAGE = [&](int t, int bi) {
    const int k0 = t << 6;
#pragma unroll
    for (int c4 = 0; c4 < 4; ++c4) {
      const int o = (c4 * 256 + tid) * 16;
      const int r = o >> 7;
      const int sc = (((o >> 4) & 7) ^ (r & 7)) << 3;
      gload_lds16(A + (bm + r) * lda + k0 + sc, &As[bi][o >> 1]);
      gload_lds16(Bt + (bn + r) * ldb + k0 + sc, &Bs[bi][o >> 1]);
    }
  };

  STAGE(0, 0);
  for (int t = 0; t < nt; ++t) {
    const int cur = t & 1;
    if (t + 1 < nt) {
      STAGE(t + 1, cur ^ 1);                            // next tile in flight over compute
      asm volatile("s_waitcnt vmcnt(8)" ::: "memory");  // tile t's 8 loads landed in LDS
    } else {
      asm volatile("s_waitcnt vmcnt(0)" ::: "memory");
    }
    __builtin_amdgcn_s_barrier();
    asm volatile("" ::: "memory");  // pin LDS reads below barrier
    bf16x8 af[4][2], bfr[4][2];
#pragma unroll
    for (int i = 0; i < 4; ++i)
#pragma unroll
      for (int ks = 0; ks < 2; ++ks) {
        const int ar = arow + i * 16;
        const int ac = ((ks * 4 + (lane >> 4)) ^ (ar & 7)) << 4;
        af[i][ks] = *(const bf16x8*)((const char*)&As[cur][0] + ar * 128 + ac);
        const int br = bcol + i * 16;
        const int bc = ((ks * 4 + (lane >> 4)) ^ (br & 7)) << 4;
        bfr[i][ks] = *(const bf16x8*)((const char*)&Bs[cur][0] + br * 128 + bc);
      }
#pragma unroll
    for (int ks = 0; ks < 2; ++ks)
#pragma unroll
      for (int i = 0; i < 4; ++i)
#pragma unroll
        for (int j = 0; j < 4; ++j)
          acc[i][j] = __builtin_amdgcn_mfma_f32_16x16x32_bf16(af[i][ks], bfr[j][ks],
                                                              acc[i][j], 0, 0, 0);
    // ds_reads must be COMPLETE (not just issued) before the closing barrier,
    // else another wave's next STAGE overwrites LDS under an in-flight read.
    asm volatile("s_waitcnt lgkmcnt(0)" ::: "memory");
    __builtin_amdgcn_sched_barrier(0);
    __builtin_amdgcn_s_barrier();
  }
}

// fat GEMM: bx<4 -> y panel (split-bf16, K=1536, f32 out); else xW panel (K=512, bf16)
__global__ __launch_bounds__(256, 2) void fat_gemm(const u16* __restrict__ Aatt,
                                                   const u16* __restrict__ Wt1,
                                                   const u16* __restrict__ Batt,
                                                   u16* __restrict__ xW, float* __restrict__ y) {
  __shared__ u16 As[2][8192];
  __shared__ u16 Bs[2][8192];
  f32x4 acc[4][4] = {};
  const int tid = threadIdx.x;
  const int lane = tid & 63;
  const int wave = tid >> 6;
  const int wr = wave >> 1, wc = wave & 1;
  int bx = blockIdx.x, by = blockIdx.y;
  xcd_swz(20, bx, by);
  const size_t bm = (size_t)by * 128;
  const bool yp = bx < 4;
  const size_t bn = yp ? (size_t)bx * 128 : (size_t)(bx - 4) * 128;

  if (yp)
    gemm_core(Aatt, Batt, 1536, 1536, 1536, bm, bn, As, Bs, acc);
  else
    gemm_core(Aatt, Wt1, 512, 1536, 512, bm, bn, As, Bs, acc);

  const size_t crow = bm + wr * 64 + ((lane >> 4) * 4);
  const size_t ccol = bn + wc * 64 + (lane & 15);
#pragma unroll
  for (int i = 0; i < 4; ++i)
#pragma unroll
    for (int j = 0; j < 4; ++j)
#pragma unroll
      for (int b = 0; b < 4; ++b) {
        size_t r = crow + i * 16 + b, c = ccol + j * 16;
        if (yp)
          y[r * 512 + c] = acc[i][j][b];
        else
          xW[r * 2048 + c] = f2bf(acc[i][j][b]);
      }
}

// layer-2 GEMM: h1W = h1 @ Wt2^T, K=512, bf16 out, ldc=2048
__global__ __launch_bounds__(256, 2) void gemm_l2(const u16* __restrict__ h1,
                                                  const u16* __restrict__ Wt2,
                                                  u16* __restrict__ h1W) {
  __shared__ u16 As[2][8192];
  __shared__ u16 Bs[2][8192];
  f32x4 acc[4][4] = {};
  const int tid = threadIdx.x;
  const int lane = tid & 63;
  const int wave = tid >> 6;
  const int wr = wave >> 1, wc = wave & 1;
  int bx = blockIdx.x, by = blockIdx.y;
  xcd_swz(16, bx, by);
  const size_t bm = (size_t)by * 128;
  const size_t bn = (size_t)bx * 128;
  gemm_core(h1, Wt2, 512, 512, 512, bm, bn, As, Bs, acc);
  const size_t crow = bm + wr * 64 + ((lane >> 4) * 4);
  const size_t ccol = bn + wc * 64 + (lane & 15);
#pragma unroll
  for (int i = 0; i < 4; ++i)
#pragma unroll
    for (int j = 0; j < 4; ++j)
#pragma unroll
      for (int b = 0; b < 4; ++b) {
        size_t r = crow + i * 16 + b, c = ccol + j * 16;
        h1W[r * 2048 + c] = f2bf(acc[i][j][b]);
      }
}

// XCD-contiguous row mapping: 4096 blocks, block b -> XCD b%8, contiguous 512-row slice.
__device__ __forceinline__ int xcd_row(int b) { return (b & 7) * 512 + (b >> 3); }

// ---------------- gather1: scores + softmax + banded aggregate + relu ----------------
__global__ void gather1(const float* __restrict__ x, const float* __restrict__ y,
                        const u16* __restrict__ xW, const int* __restrict__ spk,
                        float* __restrict__ attn, u16* __restrict__ h1) {
  const int n = xcd_row(blockIdx.x);
  const int tid = threadIdx.x;
  __shared__ float ys[512];
  __shared__ float sc[21];
  __shared__ float av[21], apv[21], asv[21];
  __shared__ int sps[21];
  const int mysp = spk[n];
  ys[tid] = y[(size_t)n * 512 + tid];
  ys[tid + 256] = y[(size_t)n * 512 + tid + 256];
  if (tid < 21) {
    int m = n + tid - 10;
    sps[tid] = (0 <= m && m < NN) ? spk[m] : -9;
  }
  __syncthreads();
  const int wave = tid >> 6, lane = tid & 63;
  for (int w = wave; w < 21; w += 4) {
    int m = n + w - 10;
    float s = 0.f;
    if (0 <= m && m < NN) {
      const float* xm = x + (size_t)m * 512;
      float p = 0.f;
#pragma unroll
      for (int i = 0; i < 8; ++i) p += xm[lane + i * 64] * ys[lane + i * 64];
#pragma unroll
      for (int off = 32; off; off >>= 1) p += __shfl_xor(p, off, 64);
      s = p;
    }
    if (lane == 0) sc[w] = s;
  }
  __syncthreads();
  if (tid < 64) {
    float v = (tid < 21) ? sc[tid] : -1e30f;
    float mx = v;
#pragma unroll
    for (int off = 32; off; off >>= 1) mx = fmaxf(mx, __shfl_xor(mx, off, 64));
    float e = (tid < 21) ? __expf(v - mx) : 0.f;
    float sum = e;
#pragma unroll
    for (int off = 32; off; off >>= 1) sum += __shfl_xor(sum, off, 64);
    if (tid < 21) {
      int m = n + tid - 10;
      float a = (0 <= m && m < NN) ? (e / sum) : 0.f;
      av[tid] = a;
      apv[tid] = (tid >= 10) ? a : 0.f;           // m >= n
      asv[tid] = (sps[tid] == mysp) ? a : 0.f;    // same speaker
      attn[(size_t)n * 24 + tid] = a;
    }
  }
  __syncthreads();
  const u32* self = (const u32*)(xW + (size_t)n * 2048);
  u32 hv = self[768 + tid];
  float a0 = bf2f((u16)hv), a1 = bf2f((u16)(hv >> 16));
  for (int w = 0; w < 21; ++w) {
    int m = n + w - 10;
    if (m < 0 || m >= NN) continue;
    float a = av[w], ap = apv[w], s2 = asv[w];
    const u32* row = (const u32*)(xW + (size_t)m * 2048);
    u32 vp = row[tid], vs = row[256 + tid], va = row[512 + tid];
    a0 += ap * bf2f((u16)vp) + s2 * bf2f((u16)vs) + a * bf2f((u16)va);
    a1 += ap * bf2f((u16)(vp >> 16)) + s2 * bf2f((u16)(vs >> 16)) + a * bf2f((u16)(va >> 16));
  }
  ((u32*)(h1 + (size_t)n * 512))[tid] = packbf(fmaxf(a0, 0.f), fmaxf(a1, 0.f));
}

// ---------------- gather2: banded aggregate + relu -> fp32 out ----------------
__global__ void gather2(const u16* __restrict__ h1W, const float* __restrict__ attn,
                        const int* __restrict__ spk, float* __restrict__ out) {
  const int n = xcd_row(blockIdx.x);
  const int tid = threadIdx.x;
  __shared__ float av[21], apv[21], asv[21];
  if (tid < 21) {
    int m = n + tid - 10;
    float a = attn[(size_t)n * 24 + tid];
    int sp = (0 <= m && m < NN) ? spk[m] : -9;
    av[tid] = a;
    apv[tid] = (tid >= 10) ? a : 0.f;
    asv[tid] = (sp == spk[n]) ? a : 0.f;
  }
  __syncthreads();
  const u32* self = (const u32*)(h1W + (size_t)n * 2048);
  u32 hv = self[768 + tid];
  float a0 = bf2f((u16)hv), a1 = bf2f((u16)(hv >> 16));
  for (int w = 0; w < 21; ++w) {
    int m = n + w - 10;
    if (m < 0 || m >= NN) continue;
    float a = av[w], ap = apv[w], s2 = asv[w];
    const u32* row = (const u32*)(h1W + (size_t)m * 2048);
    u32 vp = row[tid], vs = row[256 + tid], va = row[512 + tid];
    a0 += ap * bf2f((u16)vp) + s2 * bf2f((u16)vs) + a * bf2f((u16)va);
    a1 += ap * bf2f((u16)(vp >> 16)) + s2 * bf2f((u16)(vs >> 16)) + a * bf2f((u16)(va >> 16));
  }
  float* o = out + (size_t)n * 512 + tid * 2;
  o[0] = fmaxf(a0, 0.f);
  o[1] = fmaxf(a1, 0.f);
}

// ---------------- launch ----------------
extern "C" void kernel_launch(void* const* d_in, const int* in_sizes, int n_in,
                              void* d_out, int out_size, void* d_ws, size_t ws_size,
                              hipStream_t stream) {
  const float* x = (const float*)d_in[0];
  const int* spk = (const int*)d_in[1];
  const float* w_gc1 = (const float*)d_in[2];
  const float* w_gc2 = (const float*)d_in[3];
  const float* w_att = (const float*)d_in[4];
  const float* w_aggr1 = (const float*)d_in[5];
  const float* w_aggr2 = (const float*)d_in[6];

  char* p = (char*)d_ws;
  u16* Aatt = (u16*)p;  p += (size_t)NN * 1536 * 2;    // 12.6 MB
  u16* Batt = (u16*)p;  p += (size_t)512 * 1536 * 2;   // 1.6 MB
  u16* Wt1 = (u16*)p;   p += (size_t)2048 * 512 * 2;   // 2.1 MB
  u16* Wt2 = (u16*)p;   p += (size_t)2048 * 512 * 2;   // 2.1 MB
  float* y = (float*)p; p += (size_t)NN * 512 * 4;     // 8.4 MB
  float* attn = (float*)p; p += (size_t)NN * 24 * 4;   // 0.4 MB
  u16* xW = (u16*)p;    p += (size_t)NN * 2048 * 2;    // 16.8 MB
  u16* h1 = (u16*)p;    p += (size_t)NN * 512 * 2;     // 4.2 MB
  u16* h1W = (u16*)p;   p += (size_t)NN * 2048 * 2;    // 16.8 MB (~65 MB total)

  prep_all<<<17408, 256, 0, stream>>>(x, w_att, w_gc1, w_aggr1, w_gc2, w_aggr2,
                                      Aatt, Batt, Wt1, Wt2);

  fat_gemm<<<dim3(20, 32), 256, 0, stream>>>(Aatt, Wt1, Batt, xW, y);

  gather1<<<NN, 256, 0, stream>>>(x, y, xW, spk, attn, h1);

  gemm_l2<<<dim3(16, 32), 256, 0, stream>>>(h1, Wt2, h1W);

  gather2<<<NN, 256, 0, stream>>>(h1W, attn, spk, (float*)d_out);
}

// Round 11
// 99.677 us; speedup vs baseline: 1.8418x; 1.1283x over previous
//
#include <hip/hip_runtime.h>

// DialogueGCN on MI355X — round 10 = round 9 + branch-free pipelined gathers:
//   * xW/h1W get 16 zeroed guard rows on each side -> band loads unconditional
//   * padded fp32 copy xp of x (zero guards) for branch-free score dots
//   * gather loops fully unrolled, split w<10 (2-term) / w>=10 (3-term)
// GEMM core unchanged from round 9 (BK=64, T2 swizzle, counted vmcnt).

#define NN 4096

typedef __bf16 bf16x8 __attribute__((ext_vector_type(8)));
typedef float f32x4 __attribute__((ext_vector_type(4)));
typedef unsigned short u16;
typedef unsigned int u32;

__device__ __forceinline__ u16 f2bf(float f) {
  unsigned u = __float_as_uint(f);
  unsigned r = u + 0x7FFFu + ((u >> 16) & 1u);
  return (u16)(r >> 16);
}
__device__ __forceinline__ float bf2f(u16 h) {
  return __uint_as_float(((unsigned)h) << 16);
}
__device__ __forceinline__ float blo(u32 v) { return __uint_as_float(v << 16); }
__device__ __forceinline__ float bhi(u32 v) { return __uint_as_float(v & 0xffff0000u); }
__device__ __forceinline__ u32 packbf(float a, float b) {
  return (u32)f2bf(a) | ((u32)f2bf(b) << 16);
}

__device__ __forceinline__ void gload_lds16(const u16* g, u16* l) {
  __builtin_amdgcn_global_load_lds(
      (const __attribute__((address_space(1))) void*)g,
      (__attribute__((address_space(3))) void*)l, 16, 0, 0);
}

// ---------------- fused prep ----------------
// A [0,8192):      x -> Aatt [hi|lo|hi] and xp[r+16][c] = x (fp32 padded copy)
// B [8192,9216):   w_att -> Batt [512][1536] = [hi|hi|lo]
// W [9216,17408):  Wt[2048 j][512 k] x2 (panels gc0-gc1 | gc2-gc3 | gc1+gc3 | aggr)
// G1 [17408,17472): zero xp guard rows (0..15, 4112..4127)
// G2 [17472,17600): zero xWg guard rows
// G3 [17600,17728): zero h1Wg guard rows
__global__ void prep_all(const float* __restrict__ x, const float* __restrict__ w_att,
                         const float* __restrict__ w_gc1, const float* __restrict__ w_aggr1,
                         const float* __restrict__ w_gc2, const float* __restrict__ w_aggr2,
                         u16* __restrict__ Aatt, u16* __restrict__ Batt,
                         u16* __restrict__ Wt1, u16* __restrict__ Wt2,
                         float* __restrict__ xp, u32* __restrict__ xWg,
                         u32* __restrict__ h1Wg) {
  const int b = blockIdx.x, tid = threadIdx.x;
  if (b < 8192) {
    int idx = b * 256 + tid;
    int r = idx >> 9, c = idx & 511;
    float v = x[idx];
    u16 hi = f2bf(v), lo = f2bf(v - bf2f(hi));
    u16* row = Aatt + (size_t)r * 1536;
    row[c] = hi; row[512 + c] = lo; row[1024 + c] = hi;
    xp[(size_t)(r + 16) * 512 + c] = v;
  } else if (b < 9216) {
    int idx = (b - 8192) * 256 + tid;
    int j = idx >> 9, e = idx & 511;
    float v = w_att[(size_t)e * 512 + j];
    u16 hi = f2bf(v), lo = f2bf(v - bf2f(hi));
    u16* row = Batt + (size_t)j * 1536;
    row[e] = hi; row[512 + e] = hi; row[1024 + e] = lo;
  } else if (b < 17408) {
    int lay = (b >= 13312);
    int idx = (b - (lay ? 13312 : 9216)) * 256 + tid;  // over 2048*512
    const float* g = lay ? w_gc2 : w_gc1;
    const float* wa = lay ? w_aggr2 : w_aggr1;
    u16* Wt = lay ? Wt2 : Wt1;
    int j = idx >> 9, k = idx & 511;
    int p = j >> 9, jj = j & 511;
    size_t o = (size_t)k * 512 + jj;
    float v;
    if (p == 0)      v = g[o] - g[262144 + o];
    else if (p == 1) v = g[524288 + o] - g[786432 + o];
    else if (p == 2) v = g[262144 + o] + g[786432 + o];
    else             v = wa[o];
    Wt[(size_t)j * 512 + k] = f2bf(v);
  } else if (b < 17472) {
    int idx = (b - 17408) * 256 + tid;  // 32 rows x 512
    int g = idx >> 9, c = idx & 511;
    int row = (g < 16) ? g : 4112 + (g - 16);
    xp[(size_t)row * 512 + c] = 0.f;
  } else if (b < 17600) {
    int idx = (b - 17472) * 256 + tid;  // 32 rows x 1024 u32
    int g = idx >> 10, c = idx & 1023;
    int row = (g < 16) ? g : 4112 + (g - 16);
    xWg[(size_t)row * 1024 + c] = 0;
  } else {
    int idx = (b - 17600) * 256 + tid;
    int g = idx >> 10, c = idx & 1023;
    int row = (g < 16) ? g : 4112 + (g - 16);
    h1Wg[(size_t)row * 1024 + c] = 0;
  }
}

// XCD-aware swizzle of a 2D grid (total blocks divisible by 8)
__device__ __forceinline__ void xcd_swz(int gx, int& bx, int& by) {
  int lid = by * gx + bx;
  int cpx = (gx * (int)gridDim.y) >> 3;
  int nl = (lid & 7) * cpx + (lid >> 3);
  by = nl / gx;
  bx = nl - by * gx;
}

// ---------------- 128x128 GEMM core — BK=64, swizzled, double-buffered ----------------
__device__ __forceinline__ void gemm_core(const u16* __restrict__ A, const u16* __restrict__ Bt,
                                          int K, int lda, int ldb, size_t bm, size_t bn,
                                          u16 (&As)[2][8192], u16 (&Bs)[2][8192],
                                          f32x4 (&acc)[4][4]) {
  const int tid = threadIdx.x;
  const int lane = tid & 63;
  const int wave = tid >> 6;
  const int wr = wave >> 1, wc = wave & 1;
  const int arow = wr * 64 + (lane & 15);
  const int bcol = wc * 64 + (lane & 15);
  const int nt = K >> 6;

  auto STAGE = [&](int t, int bi) {
    const int k0 = t << 6;
#pragma unroll
    for (int c4 = 0; c4 < 4; ++c4) {
      const int o = (c4 * 256 + tid) * 16;
      const int r = o >> 7;
      const int sc = (((o >> 4) & 7) ^ (r & 7)) << 3;
      gload_lds16(A + (bm + r) * lda + k0 + sc, &As[bi][o >> 1]);
      gload_lds16(Bt + (bn + r) * ldb + k0 + sc, &Bs[bi][o >> 1]);
    }
  };

  STAGE(0, 0);
  for (int t = 0; t < nt; ++t) {
    const int cur = t & 1;
    if (t + 1 < nt) {
      STAGE(t + 1, cur ^ 1);
      asm volatile("s_waitcnt vmcnt(8)" ::: "memory");
    } else {
      asm volatile("s_waitcnt vmcnt(0)" ::: "memory");
    }
    __builtin_amdgcn_s_barrier();
    asm volatile("" ::: "memory");
    bf16x8 af[4][2], bfr[4][2];
#pragma unroll
    for (int i = 0; i < 4; ++i)
#pragma unroll
      for (int ks = 0; ks < 2; ++ks) {
        const int ar = arow + i * 16;
        const int ac = ((ks * 4 + (lane >> 4)) ^ (ar & 7)) << 4;
        af[i][ks] = *(const bf16x8*)((const char*)&As[cur][0] + ar * 128 + ac);
        const int br = bcol + i * 16;
        const int bc = ((ks * 4 + (lane >> 4)) ^ (br & 7)) << 4;
        bfr[i][ks] = *(const bf16x8*)((const char*)&Bs[cur][0] + br * 128 + bc);
      }
#pragma unroll
    for (int ks = 0; ks < 2; ++ks)
#pragma unroll
      for (int i = 0; i < 4; ++i)
#pragma unroll
        for (int j = 0; j < 4; ++j)
          acc[i][j] = __builtin_amdgcn_mfma_f32_16x16x32_bf16(af[i][ks], bfr[j][ks],
                                                              acc[i][j], 0, 0, 0);
    asm volatile("s_waitcnt lgkmcnt(0)" ::: "memory");
    __builtin_amdgcn_sched_barrier(0);
    __builtin_amdgcn_s_barrier();
  }
}

// fat GEMM: bx<4 -> y panel (split-bf16, K=1536, f32 out); else xW panel (K=512, bf16)
__global__ __launch_bounds__(256, 2) void fat_gemm(const u16* __restrict__ Aatt,
                                                   const u16* __restrict__ Wt1,
                                                   const u16* __restrict__ Batt,
                                                   u16* __restrict__ xW, float* __restrict__ y) {
  __shared__ u16 As[2][8192];
  __shared__ u16 Bs[2][8192];
  f32x4 acc[4][4] = {};
  const int tid = threadIdx.x;
  const int lane = tid & 63;
  const int wave = tid >> 6;
  const int wr = wave >> 1, wc = wave & 1;
  int bx = blockIdx.x, by = blockIdx.y;
  xcd_swz(20, bx, by);
  const size_t bm = (size_t)by * 128;
  const bool yp = bx < 4;
  const size_t bn = yp ? (size_t)bx * 128 : (size_t)(bx - 4) * 128;

  if (yp)
    gemm_core(Aatt, Batt, 1536, 1536, 1536, bm, bn, As, Bs, acc);
  else
    gemm_core(Aatt, Wt1, 512, 1536, 512, bm, bn, As, Bs, acc);

  const size_t crow = bm + wr * 64 + ((lane >> 4) * 4);
  const size_t ccol = bn + wc * 64 + (lane & 15);
#pragma unroll
  for (int i = 0; i < 4; ++i)
#pragma unroll
    for (int j = 0; j < 4; ++j)
#pragma unroll
      for (int b = 0; b < 4; ++b) {
        size_t r = crow + i * 16 + b, c = ccol + j * 16;
        if (yp)
          y[r * 512 + c] = acc[i][j][b];
        else
          xW[r * 2048 + c] = f2bf(acc[i][j][b]);
      }
}

// layer-2 GEMM: h1W = h1 @ Wt2^T, K=512, bf16 out, ldc=2048
__global__ __launch_bounds__(256, 2) void gemm_l2(const u16* __restrict__ h1,
                                                  const u16* __restrict__ Wt2,
                                                  u16* __restrict__ h1W) {
  __shared__ u16 As[2][8192];
  __shared__ u16 Bs[2][8192];
  f32x4 acc[4][4] = {};
  const int tid = threadIdx.x;
  const int lane = tid & 63;
  const int wave = tid >> 6;
  const int wr = wave >> 1, wc = wave & 1;
  int bx = blockIdx.x, by = blockIdx.y;
  xcd_swz(16, bx, by);
  const size_t bm = (size_t)by * 128;
  const size_t bn = (size_t)bx * 128;
  gemm_core(h1, Wt2, 512, 512, 512, bm, bn, As, Bs, acc);
  const size_t crow = bm + wr * 64 + ((lane >> 4) * 4);
  const size_t ccol = bn + wc * 64 + (lane & 15);
#pragma unroll
  for (int i = 0; i < 4; ++i)
#pragma unroll
    for (int j = 0; j < 4; ++j)
#pragma unroll
      for (int b = 0; b < 4; ++b) {
        size_t r = crow + i * 16 + b, c = ccol + j * 16;
        h1W[r * 2048 + c] = f2bf(acc[i][j][b]);
      }
}

// XCD-contiguous row mapping: 4096 blocks, block b -> XCD b%8, contiguous 512-row slice.
__device__ __forceinline__ int xcd_row(int b) { return (b & 7) * 512 + (b >> 3); }

// ---------------- gather1: scores + softmax + banded aggregate + relu ----------------
__global__ void gather1(const float* __restrict__ xp, const float* __restrict__ y,
                        const u16* __restrict__ xW, const int* __restrict__ spk,
                        float* __restrict__ attn, u16* __restrict__ h1) {
  const int n = xcd_row(blockIdx.x);
  const int tid = threadIdx.x;
  __shared__ float ys[512];
  __shared__ float sc[21];
  __shared__ float av[21], apv[21], asv[21];
  __shared__ int sps[21];
  const int mysp = spk[n];
  ys[tid] = y[(size_t)n * 512 + tid];
  ys[tid + 256] = y[(size_t)n * 512 + tid + 256];
  if (tid < 21) {
    int m = n + tid - 10;
    sps[tid] = (0 <= m && m < NN) ? spk[m] : -9;
  }
  __syncthreads();
  const int wave = tid >> 6, lane = tid & 63;
  for (int w = wave; w < 21; w += 4) {
    const float* xm = xp + (size_t)(n + 6 + w) * 512;  // guards are zero -> OOB dot = 0
    float p = 0.f;
#pragma unroll
    for (int i = 0; i < 8; ++i) p += xm[lane + i * 64] * ys[lane + i * 64];
#pragma unroll
    for (int off = 32; off; off >>= 1) p += __shfl_xor(p, off, 64);
    if (lane == 0) sc[w] = p;
  }
  __syncthreads();
  if (tid < 64) {
    float v = (tid < 21) ? sc[tid] : -1e30f;
    float mx = v;
#pragma unroll
    for (int off = 32; off; off >>= 1) mx = fmaxf(mx, __shfl_xor(mx, off, 64));
    float e = (tid < 21) ? __expf(v - mx) : 0.f;
    float sum = e;
#pragma unroll
    for (int off = 32; off; off >>= 1) sum += __shfl_xor(sum, off, 64);
    if (tid < 21) {
      int m = n + tid - 10;
      float a = (0 <= m && m < NN) ? (e / sum) : 0.f;
      av[tid] = a;
      apv[tid] = (tid >= 10) ? a : 0.f;
      asv[tid] = (sps[tid] == mysp) ? a : 0.f;
      attn[(size_t)n * 24 + tid] = a;
    }
  }
  __syncthreads();
  const u32* xW32 = (const u32*)xW;
  u32 hv = xW32[(size_t)n * 1024 + 768 + tid];
  float a0 = blo(hv), a1 = bhi(hv);
  // branch-free banded aggregation (guard rows carry zero weight)
#pragma unroll
  for (int w = 0; w < 10; ++w) {  // pred weight is 0 here: 2 terms
    const u32* row = xW32 + (ptrdiff_t)(n - 10 + w) * 1024 + tid;
    u32 vs = row[256], va = row[512];
    float s2 = asv[w], a = av[w];
    a0 += s2 * blo(vs) + a * blo(va);
    a1 += s2 * bhi(vs) + a * bhi(va);
  }
#pragma unroll
  for (int w = 10; w < 21; ++w) {  // 3 terms
    const u32* row = xW32 + (ptrdiff_t)(n - 10 + w) * 1024 + tid;
    u32 vp = row[0], vs = row[256], va = row[512];
    float ap = apv[w], s2 = asv[w], a = av[w];
    a0 += ap * blo(vp) + s2 * blo(vs) + a * blo(va);
    a1 += ap * bhi(vp) + s2 * bhi(vs) + a * bhi(va);
  }
  ((u32*)(h1 + (size_t)n * 512))[tid] = packbf(fmaxf(a0, 0.f), fmaxf(a1, 0.f));
}

// ---------------- gather2: banded aggregate + relu -> fp32 out ----------------
__global__ void gather2(const u16* __restrict__ h1W, const float* __restrict__ attn,
                        const int* __restrict__ spk, float* __restrict__ out) {
  const int n = xcd_row(blockIdx.x);
  const int tid = threadIdx.x;
  __shared__ float av[21], apv[21], asv[21];
  if (tid < 21) {
    int m = n + tid - 10;
    float a = attn[(size_t)n * 24 + tid];
    int sp = (0 <= m && m < NN) ? spk[m] : -9;
    av[tid] = a;
    apv[tid] = (tid >= 10) ? a : 0.f;
    asv[tid] = (sp == spk[n]) ? a : 0.f;
  }
  __syncthreads();
  const u32* hW32 = (const u32*)h1W;
  u32 hv = hW32[(size_t)n * 1024 + 768 + tid];
  float a0 = blo(hv), a1 = bhi(hv);
#pragma unroll
  for (int w = 0; w < 10; ++w) {
    const u32* row = hW32 + (ptrdiff_t)(n - 10 + w) * 1024 + tid;
    u32 vs = row[256], va = row[512];
    float s2 = asv[w], a = av[w];
    a0 += s2 * blo(vs) + a * blo(va);
    a1 += s2 * bhi(vs) + a * bhi(va);
  }
#pragma unroll
  for (int w = 10; w < 21; ++w) {
    const u32* row = hW32 + (ptrdiff_t)(n - 10 + w) * 1024 + tid;
    u32 vp = row[0], vs = row[256], va = row[512];
    float ap = apv[w], s2 = asv[w], a = av[w];
    a0 += ap * blo(vp) + s2 * blo(vs) + a * blo(va);
    a1 += ap * bhi(vp) + s2 * bhi(vs) + a * bhi(va);
  }
  float* o = out + (size_t)n * 512 + tid * 2;
  o[0] = fmaxf(a0, 0.f);
  o[1] = fmaxf(a1, 0.f);
}

// ---------------- launch ----------------
extern "C" void kernel_launch(void* const* d_in, const int* in_sizes, int n_in,
                              void* d_out, int out_size, void* d_ws, size_t ws_size,
                              hipStream_t stream) {
  const float* x = (const float*)d_in[0];
  const int* spk = (const int*)d_in[1];
  const float* w_gc1 = (const float*)d_in[2];
  const float* w_gc2 = (const float*)d_in[3];
  const float* w_att = (const float*)d_in[4];
  const float* w_aggr1 = (const float*)d_in[5];
  const float* w_aggr2 = (const float*)d_in[6];

  char* p = (char*)d_ws;
  u16* Aatt = (u16*)p;  p += (size_t)NN * 1536 * 2;     // 12.6 MB
  u16* Batt = (u16*)p;  p += (size_t)512 * 1536 * 2;    // 1.6 MB
  u16* Wt1 = (u16*)p;   p += (size_t)2048 * 512 * 2;    // 2.1 MB
  u16* Wt2 = (u16*)p;   p += (size_t)2048 * 512 * 2;    // 2.1 MB
  float* xp = (float*)p; p += (size_t)4128 * 512 * 4;   // 8.5 MB (16 guard rows each side)
  float* y = (float*)p; p += (size_t)NN * 512 * 4;      // 8.4 MB
  float* attn = (float*)p; p += (size_t)NN * 24 * 4;    // 0.4 MB
  u16* xWg = (u16*)p;   p += (size_t)4128 * 2048 * 2;   // 16.9 MB
  u16* h1 = (u16*)p;    p += (size_t)NN * 512 * 2;      // 4.2 MB
  u16* h1Wg = (u16*)p;  p += (size_t)4128 * 2048 * 2;   // 16.9 MB (~73.6 MB total)

  u16* xW = xWg + (size_t)16 * 2048;   // row 0 of real data
  u16* h1W = h1Wg + (size_t)16 * 2048;

  prep_all<<<17728, 256, 0, stream>>>(x, w_att, w_gc1, w_aggr1, w_gc2, w_aggr2,
                                      Aatt, Batt, Wt1, Wt2, xp, (u32*)xWg, (u32*)h1Wg);

  fat_gemm<<<dim3(20, 32), 256, 0, stream>>>(Aatt, Wt1, Batt, xW, y);

  gather1<<<NN, 256, 0, stream>>>(xp, y, xW, spk, attn, h1);

  gemm_l2<<<dim3(16, 32), 256, 0, stream>>>(h1, Wt2, h1W);

  gather2<<<NN, 256, 0, stream>>>(h1W, attn, spk, (float*)d_out);
}